// Round 2
// baseline (22740.331 us; speedup 1.0000x reference)
//
#include <hip/hip_runtime.h>

typedef __attribute__((ext_vector_type(8))) short short8;
typedef __attribute__((ext_vector_type(4))) float f32x4;

#define T_STEPS 512
#define BATCH 64
#define HID 1024
#define NWG 64

__device__ __forceinline__ unsigned short f2bf(float f) {
  union { float f; unsigned u; } v; v.f = f;
  return (unsigned short)((v.u + 0x7FFFu + ((v.u >> 16) & 1u)) >> 16);
}

// ---------------- conversion ----------------
__global__ void k_f32_to_bf16(const float* __restrict__ src,
                              unsigned short* __restrict__ dst, int n4) {
  int i = blockIdx.x * blockDim.x + threadIdx.x;
  if (i >= n4) return;
  float4 v = ((const float4*)src)[i];
  unsigned long long p = (unsigned long long)f2bf(v.x)
                       | ((unsigned long long)f2bf(v.y) << 16)
                       | ((unsigned long long)f2bf(v.z) << 32)
                       | ((unsigned long long)f2bf(v.w) << 48);
  ((unsigned long long*)dst)[i] = p;
}

__global__ void k_sentinel(float* out) { out[threadIdx.x] = 12345.0f; }

// ---------------- big GEMM: C(M,N) = A(M,K) * B(N,K)^T + bias(N) ----------------
__global__ __launch_bounds__(256) void k_gemm_bias(
    const unsigned short* __restrict__ A,
    const unsigned short* __restrict__ Bm,
    const float* __restrict__ bias,
    float* __restrict__ C) {
  constexpr int K = 1024, N = 3072;
  constexpr int LS = 40;
  __shared__ unsigned short As[128 * LS];
  __shared__ unsigned short Bs[128 * LS];
  const int tid = threadIdx.x;
  const int lane = tid & 63;
  const int w = tid >> 6;
  const int wm = (w >> 1) * 64, wn = (w & 1) * 64;
  const int m0 = blockIdx.y * 128, n0 = blockIdx.x * 128;
  const int q = lane >> 4, ln = lane & 15;
  const int r = tid >> 2;
  const int c8 = (tid & 3) * 8;

  f32x4 acc[4][4] = {};

  for (int k0 = 0; k0 < K; k0 += 32) {
#pragma unroll
    for (int p = 0; p < 2; ++p) {
      int row = r + p * 64;
      *(short8*)&As[row * LS + c8] = *(const short8*)&A[(long)(m0 + row) * K + k0 + c8];
      *(short8*)&Bs[row * LS + c8] = *(const short8*)&Bm[(long)(n0 + row) * K + k0 + c8];
    }
    __syncthreads();
    short8 af[4], bfr[4];
#pragma unroll
    for (int i = 0; i < 4; ++i) af[i] = *(short8*)&As[(wm + i * 16 + ln) * LS + q * 8];
#pragma unroll
    for (int i = 0; i < 4; ++i) bfr[i] = *(short8*)&Bs[(wn + i * 16 + ln) * LS + q * 8];
#pragma unroll
    for (int im = 0; im < 4; ++im)
#pragma unroll
      for (int in = 0; in < 4; ++in)
        acc[im][in] = __builtin_amdgcn_mfma_f32_16x16x32_bf16(af[im], bfr[in], acc[im][in], 0, 0, 0);
    __syncthreads();
  }
#pragma unroll
  for (int im = 0; im < 4; ++im) {
    int mrow = m0 + wm + im * 16 + q * 4;
#pragma unroll
    for (int in = 0; in < 4; ++in) {
      int ncol = n0 + wn + in * 16 + ln;
      float bv = bias[ncol];
#pragma unroll
      for (int j = 0; j < 4; ++j)
        C[(long)(mrow + j) * N + ncol] = acc[im][in][j] + bv;
    }
  }
}

// ---------------- contention-free grid barrier ----------------
// flags[i] = generation of WG i. Arrival: one release STORE (no RMW round-trip).
// Wait: wave 0's 64 lanes each poll one flag (4 cachelines), then acquire fence.
__device__ __forceinline__ void gbar(unsigned* flags, unsigned gen) {
  __syncthreads();
  if (threadIdx.x == 0)
    __hip_atomic_store(&flags[blockIdx.x], gen, __ATOMIC_RELEASE, __HIP_MEMORY_SCOPE_AGENT);
  if (threadIdx.x < NWG) {
    int spins = 0;
    while (__hip_atomic_load(&flags[threadIdx.x], __ATOMIC_RELAXED,
                             __HIP_MEMORY_SCOPE_AGENT) < gen) {
      __builtin_amdgcn_s_sleep(1);
      if (++spins > (1 << 16)) break;  // failsafe: wrong answer beats a hang
    }
  }
  __builtin_amdgcn_fence(__ATOMIC_ACQUIRE, "agent");
  __syncthreads();
}

// ---------------- persistent GRU recurrence ----------------
// 64 WGs x 256 thr. WG owns 16 output features; weights LDS-resident in
// MFMA fragment order [gate][kk][lane] -> conflict-free ds_read_b128.
__global__ __launch_bounds__(256, 1) void k_gru_rec(
    const float* __restrict__ gx,           // (T,B,3,H) fp32
    const unsigned short* __restrict__ Wh,  // (3,H,H) bf16, this layer
    unsigned short* __restrict__ h16,       // (B,H) bf16 state (zeroed)
    unsigned short* __restrict__ hr16,      // (B,H) bf16 h*r
    unsigned short* __restrict__ ys16,      // (T,B,H) bf16 (layer 0)
    float* __restrict__ outh,               // (T,B,H) fp32 (layer 1)
    float* __restrict__ outs,               // (B,H) fp32 final state slice
    unsigned* __restrict__ bar, int layer) {
  __shared__ short8 Wf[3 * 32 * 64];  // 96 KB
  const int tid = threadIdx.x;
  const int lane = tid & 63;
  const int wv = tid >> 6;
  const int q = lane >> 4, ln = lane & 15;
  const int c0 = blockIdx.x * 16;
  const int m0 = wv * 16;

  // stage weights: Wf[((g*32+kk)*64 + lane)] = Wh[g][c0 + (lane&15)][kk*32 + (lane>>4)*8 ..+8]
  for (int i = tid; i < 3 * 32 * 64; i += 256) {
    int g = i >> 11;
    int rem = i & 2047;
    int kk = rem >> 6;
    int l2 = rem & 63;
    int ln2 = l2 & 15, q2 = l2 >> 4;
    Wf[i] = *(const short8*)&Wh[((long)g * HID + (c0 + ln2)) * HID + kk * 32 + q2 * 8];
  }
  __syncthreads();

  unsigned gen = 0;
  const int rowA = m0 + ln;     // A-fragment row for this lane
  const int jrow = m0 + q * 4;  // C/D base row

  float hold[4] = {0.f, 0.f, 0.f, 0.f};  // register-carried h (own element)
  float gr[4], gz[4], gc[4];
#pragma unroll
  for (int j = 0; j < 4; ++j) {  // prefetch t=0 gates
    long rowidx = (long)(jrow + j) * 3;
    gr[j] = gx[(rowidx + 0) * HID + c0 + ln];
    gz[j] = gx[(rowidx + 1) * HID + c0 + ln];
    gc[j] = gx[(rowidx + 2) * HID + c0 + ln];
  }

  for (int t = 0; t < T_STEPS; ++t) {
    // ---- phase 1: r,z over full h ----
    f32x4 accr = {0.f, 0.f, 0.f, 0.f}, accz = {0.f, 0.f, 0.f, 0.f};
#pragma unroll 8
    for (int kk = 0; kk < 32; ++kk) {
      short8 a = *(const short8*)&h16[(long)rowA * HID + kk * 32 + q * 8];
      accr = __builtin_amdgcn_mfma_f32_16x16x32_bf16(a, Wf[(0 * 32 + kk) * 64 + lane], accr, 0, 0, 0);
      accz = __builtin_amdgcn_mfma_f32_16x16x32_bf16(a, Wf[(1 * 32 + kk) * 64 + lane], accz, 0, 0, 0);
    }
#pragma unroll
    for (int j = 0; j < 4; ++j) {
      float rr = 1.0f / (1.0f + __expf(-(gr[j] + accr[j])));
      hr16[(long)(jrow + j) * HID + c0 + ln] = f2bf(hold[j] * rr);
    }
    gbar(bar, ++gen);

    // ---- phase 2: c over full h*r ----
    f32x4 accc = {0.f, 0.f, 0.f, 0.f};
#pragma unroll 8
    for (int kk = 0; kk < 32; ++kk) {
      short8 a = *(const short8*)&hr16[(long)rowA * HID + kk * 32 + q * 8];
      accc = __builtin_amdgcn_mfma_f32_16x16x32_bf16(a, Wf[(2 * 32 + kk) * 64 + lane], accc, 0, 0, 0);
    }
    const long tb = (long)t * BATCH;
#pragma unroll
    for (int j = 0; j < 4; ++j) {
      float zz = 1.0f / (1.0f + __expf(-(gz[j] + accz[j])));
      float cc = tanhf(gc[j] + accc[j]);
      float hn = zz * hold[j] + (1.0f - zz) * cc;
      hold[j] = hn;
      long pos = (long)(jrow + j) * HID + c0 + ln;
      h16[pos] = f2bf(hn);
      if (layer == 0) ys16[(tb + jrow + j) * HID + c0 + ln] = f2bf(hn);
      else            outh[(tb + jrow + j) * HID + c0 + ln] = hn;
    }
    if (t == T_STEPS - 1) {
#pragma unroll
      for (int j = 0; j < 4; ++j)
        outs[(long)(jrow + j) * HID + c0 + ln] = hold[j];
    }
    // prefetch next step's gates into registers before the tail barrier
    if (t + 1 < T_STEPS) {
      const long tb2 = (long)(t + 1) * BATCH;
#pragma unroll
      for (int j = 0; j < 4; ++j) {
        long rowidx = (tb2 + jrow + j) * 3;
        gr[j] = gx[(rowidx + 0) * HID + c0 + ln];
        gz[j] = gx[(rowidx + 1) * HID + c0 + ln];
        gc[j] = gx[(rowidx + 2) * HID + c0 + ln];
      }
    }
    gbar(bar, ++gen);
  }
}

// ---------------- launch ----------------
extern "C" void kernel_launch(void* const* d_in, const int* in_sizes, int n_in,
                              void* d_out, int out_size, void* d_ws, size_t ws_size,
                              hipStream_t stream) {
  const float* x = (const float*)d_in[0];
  const float* Wx = (const float*)d_in[1];
  const float* bx = (const float*)d_in[2];
  const float* Wh = (const float*)d_in[3];
  float* out = (float*)d_out;

  const size_t SZ_GX = (size_t)T_STEPS * BATCH * 3 * HID * 4;
  const size_t SZ_HID = (size_t)T_STEPS * BATCH * HID * 2;
  const size_t SZ_W16 = (size_t)2 * 3 * HID * HID * 2;
  const size_t NEEDED = SZ_GX + SZ_HID + 2 * SZ_W16 +
                        2 * (size_t)BATCH * HID * 2 + 512;
  if (ws_size < NEEDED) {
    k_sentinel<<<1, 64, 0, stream>>>(out);
    return;
  }

  char* ws = (char*)d_ws;
  size_t off = 0;
  float* gx32 = (float*)(ws + off); off += SZ_GX;
  unsigned short* hid16 = (unsigned short*)(ws + off); off += SZ_HID;
  unsigned short* Wx16 = (unsigned short*)(ws + off); off += SZ_W16;
  unsigned short* Wh16 = (unsigned short*)(ws + off); off += SZ_W16;
  unsigned short* h16 = (unsigned short*)(ws + off); off += (size_t)BATCH * HID * 2;
  unsigned short* hr16 = (unsigned short*)(ws + off); off += (size_t)BATCH * HID * 2;
  unsigned* bar = (unsigned*)(ws + off); off += 512;

  {
    int n4 = T_STEPS * BATCH * HID / 4;
    k_f32_to_bf16<<<(n4 + 255) / 256, 256, 0, stream>>>(x, hid16, n4);
  }
  {
    int n4 = 2 * 3 * HID * HID / 4;
    k_f32_to_bf16<<<(n4 + 255) / 256, 256, 0, stream>>>(Wx, Wx16, n4);
    k_f32_to_bf16<<<(n4 + 255) / 256, 256, 0, stream>>>(Wh, Wh16, n4);
  }

  float* outh = out;
  float* outs = out + (size_t)T_STEPS * BATCH * HID;

  for (int l = 0; l < 2; ++l) {
    k_gemm_bias<<<dim3(3072 / 128, 32768 / 128), 256, 0, stream>>>(
        hid16, Wx16 + (size_t)l * 3 * HID * HID, bx + (size_t)l * 3 * HID, gx32);
    hipMemsetAsync(h16, 0, (size_t)BATCH * HID * 2, stream);
    hipMemsetAsync(bar, 0, 512, stream);
    k_gru_rec<<<NWG, 256, 0, stream>>>(
        gx32, Wh16 + (size_t)l * 3 * HID * HID, h16, hr16,
        hid16, outh, outs + (size_t)l * BATCH * HID, bar, l);
  }
}